// Round 7
// baseline (195.842 us; speedup 1.0000x reference)
//
#include <hip/hip_runtime.h>

typedef __attribute__((ext_vector_type(8))) short short8;
typedef __attribute__((ext_vector_type(4))) short s16x4;
typedef __attribute__((ext_vector_type(8))) __bf16 bf16x8;
typedef __attribute__((ext_vector_type(4))) __bf16 bf16x4;
typedef __attribute__((ext_vector_type(2))) __bf16 bf16x2;
typedef __attribute__((ext_vector_type(4))) float f32x4;
typedef __attribute__((ext_vector_type(2))) float f32x2;
typedef __attribute__((ext_vector_type(4))) unsigned uint4v;
typedef __attribute__((ext_vector_type(2))) unsigned uint2v;

__device__ inline f32x4 mfma_bf16(short8 a, short8 b, f32x4 c) {
    return __builtin_amdgcn_mfma_f32_16x16x32_bf16(
        __builtin_bit_cast(bf16x8, a), __builtin_bit_cast(bf16x8, b), c, 0, 0, 0);
}
// K=16 bf16 MFMA: A-frag layout A[m=l16][k=quad*4+j] == C/D layout of a prior
// MFMA transposed -> P needs no layout transform.
__device__ inline f32x4 mfma16(uint2v a, uint2v b, f32x4 c) {
#if __has_builtin(__builtin_amdgcn_mfma_f32_16x16x16_bf16)
    return __builtin_amdgcn_mfma_f32_16x16x16_bf16(
        __builtin_bit_cast(bf16x4, a), __builtin_bit_cast(bf16x4, b), c, 0, 0, 0);
#else
    return __builtin_amdgcn_mfma_f32_16x16x16bf16_1k(
        __builtin_bit_cast(s16x4, a), __builtin_bit_cast(s16x4, b), c, 0, 0, 0);
#endif
}

// fast exp2: bare v_exp_f32
__device__ inline float fexp2(float x) {
#if __has_builtin(__builtin_amdgcn_exp2f)
    return __builtin_amdgcn_exp2f(x);
#else
    return exp2f(x);
#endif
}

// fp32 -> bf16 via HW convert (v_cvt_pk_bf16_f32 on gfx950), RNE
__device__ inline short f2b(float f) {
    __bf16 h = (__bf16)f;
    return __builtin_bit_cast(short, h);
}
__device__ inline unsigned pkbf(float a, float b) {
    f32x2 v; v[0] = a; v[1] = b;
    bf16x2 h = __builtin_convertvector(v, bf16x2);
    return __builtin_bit_cast(unsigned, h);
}

__device__ inline short8 ld8(const short* p) { return *(const short8*)p; }
__device__ inline short8 ld8(const float* p) {
    f32x4 a = *(const f32x4*)p;
    f32x4 b = *(const f32x4*)(p + 4);
    uint4v q;
    q[0] = pkbf(a[0], a[1]); q[1] = pkbf(a[2], a[3]);
    q[2] = pkbf(b[0], b[1]); q[3] = pkbf(b[2], b[3]);
    return __builtin_bit_cast(short8, q);
}
__device__ inline void storeC(short* C, size_t i, float v) { C[i] = f2b(v); }
__device__ inline void storeC(float* C, size_t i, float v) { C[i] = v; }

// async global->LDS DMA, 16B per lane. LDS dest must be wave-uniform base;
// HW writes lane l at base + l*16 (m104/m108: no per-lane LDS scatter).
__device__ inline void gload16(const short* g, short* l) {
    __builtin_amdgcn_global_load_lds(
        (const __attribute__((address_space(1))) unsigned*)g,
        (__attribute__((address_space(3))) unsigned*)l, 16, 0, 0);
}

// log2(e)/32 : folded into Q so softmax uses exp2 (bare v_exp_f32)
#define QSCALE 0.04508422052265167f

// ---------------------------------------------------------------------------
// Fused prep: one launch does
//   blocks [0,2048):    x fp32 -> xbf bf16 bulk convert
//   blocks [2048,2816): Wqkv [1024][3072] -> wqkvt [3072][1024] bf16 k-major
//   blocks [2816,3072): Wout [1024][1024] -> woutt [1024][1024] bf16 k-major
// ---------------------------------------------------------------------------
__global__ __launch_bounds__(256) void prep(
    const float* __restrict__ x, short* __restrict__ xb,
    const float* __restrict__ Wqkv, short* __restrict__ wqkvt,
    const float* __restrict__ Wout, short* __restrict__ woutt)
{
    const int bid = blockIdx.x;
    const int tid = threadIdx.x;
    if (bid < 2048) {
        size_t i = ((size_t)bid * 256 + tid) * 8;
        *(short8*)(xb + i) = ld8(x + i);
        return;
    }
    __shared__ short T[64 * 72];
    const float* W; short* Wt; int K, N, n0, k0;
    if (bid < 2816) {
        const int b2 = bid - 2048;
        W = Wqkv; Wt = wqkvt; K = 1024; N = 3072;
        n0 = (b2 % 48) * 64; k0 = (b2 / 48) * 64;
    } else {
        const int b3 = bid - 2816;
        W = Wout; Wt = woutt; K = 1024; N = 1024;
        n0 = (b3 & 15) * 64; k0 = (b3 >> 4) * 64;
    }
    {
        const int kl = tid >> 2, nc = (tid & 3) * 16;
        const float* src = W + (size_t)(k0 + kl) * N + n0 + nc;
        float v[16];
        *(f32x4*)&v[0]  = *(const f32x4*)(src + 0);
        *(f32x4*)&v[4]  = *(const f32x4*)(src + 4);
        *(f32x4*)&v[8]  = *(const f32x4*)(src + 8);
        *(f32x4*)&v[12] = *(const f32x4*)(src + 12);
        #pragma unroll
        for (int j = 0; j < 16; ++j) T[(nc + j) * 72 + kl] = f2b(v[j]);
    }
    __syncthreads();
    {
        const int nl = tid >> 2, kc = (tid & 3) * 16;
        short8 w0 = *(const short8*)&T[nl * 72 + kc];
        short8 w1 = *(const short8*)&T[nl * 72 + kc + 8];
        short* dst = Wt + (size_t)(n0 + nl) * K + k0 + kc;
        *(short8*)dst = w0;
        *(short8*)(dst + 8) = w1;
    }
}

// ---------------------------------------------------------------------------
// V transpose: qkv (B*N,3072) bf16 cols 2048+h*64 -> vt[(b*16+h)][dim][2048].
// ---------------------------------------------------------------------------
__global__ __launch_bounds__(256) void vtrans(
    const short* __restrict__ qkv, short* __restrict__ vt)
{
    __shared__ short T[64 * 72];
    const int tid = threadIdx.x;
    const int nt = blockIdx.x * 64, bh = blockIdx.y;
    const int b = bh >> 4, h = bh & 15;
    {
        const int tok = tid >> 2, dc = (tid & 3) * 16;
        const short* src = qkv + ((size_t)b * 2048 + nt + tok) * 3072 + 2048 + h * 64 + dc;
        short8 v0 = *(const short8*)src;
        short8 v1 = *(const short8*)(src + 8);
        #pragma unroll
        for (int j = 0; j < 8; ++j) {
            T[(dc + j) * 72 + tok]     = v0[j];
            T[(dc + 8 + j) * 72 + tok] = v1[j];
        }
    }
    __syncthreads();
    {
        const int dim = tid >> 2, kc = (tid & 3) * 16;
        short8 w0 = *(const short8*)&T[dim * 72 + kc];
        short8 w1 = *(const short8*)&T[dim * 72 + kc + 8];
        short* dst = vt + ((size_t)bh * 64 + dim) * 2048 + nt + kc;
        *(short8*)dst = w0;
        *(short8*)(dst + 8) = w1;
    }
}

// ---------------------------------------------------------------------------
// GEMM: global_load_lds DMA staging + double-buffered LDS 2-phase pipeline.
// C = A @ Bt^T (+bias). 128x128 tile, BK=32, 4 waves 2x2 (64x64 each).
// STAGE(next) issued BEFORE COMPUTE(cur); one barrier per K-step.
// Bank-swizzle: source chunk c ^ ((row>>1)&3), read slot quad ^ ((l16>>1)&3).
// QSC: scale cols<1024 by log2(e)/32 (Q pre-scale for exp2 softmax).
// ---------------------------------------------------------------------------
template <bool QSC, bool ADD_BIAS, typename TC>
__global__ __launch_bounds__(256) void gemm128(
    const short* __restrict__ A, const short* __restrict__ Bt,
    const float* __restrict__ bias, TC* __restrict__ C,
    int M, int N, int K, int lda)
{
    __shared__ short A_s0[128 * 32];
    __shared__ short A_s1[128 * 32];
    __shared__ short B_s0[128 * 32];
    __shared__ short B_s1[128 * 32];
    const int tid  = threadIdx.x;
    const int lane = tid & 63;
    const int wave = tid >> 6;
    const int quad = lane >> 4;
    const int l16  = lane & 15;
    const int wr   = wave >> 1;
    const int wc   = wave & 1;
    const int bm   = blockIdx.y * 128;
    const int bn   = blockIdx.x * 128;

    f32x4 acc[4][4];
    #pragma unroll
    for (int i = 0; i < 4; ++i)
        #pragma unroll
        for (int j = 0; j < 4; ++j)
            acc[i][j] = f32x4{0.f, 0.f, 0.f, 0.f};

    const int srow = tid >> 2;
    const int schk = tid & 3;
    const int sg   = (schk ^ ((srow >> 1) & 3)) * 8;
    const short* ap0 = A  + (size_t)(bm + srow) * lda + sg;
    const short* ap1 = A  + (size_t)(bm + 64 + srow) * lda + sg;
    const short* bp0 = Bt + (size_t)(bn + srow) * K   + sg;
    const short* bp1 = Bt + (size_t)(bn + 64 + srow) * K   + sg;
    const int lofs0 = wave * 512;
    const int lofs1 = 2048 + wave * 512;

    const int xr = (quad ^ ((l16 >> 1) & 3)) * 8;

#define STAGE_G(As, Bs, koff)                  \
    gload16(ap0 + (koff), (As) + lofs0);       \
    gload16(ap1 + (koff), (As) + lofs1);       \
    gload16(bp0 + (koff), (Bs) + lofs0);       \
    gload16(bp1 + (koff), (Bs) + lofs1);

#define COMPUTE_G(As, Bs)                                                   \
    {                                                                       \
        short8 a[4], b[4];                                                  \
        _Pragma("unroll")                                                   \
        for (int i = 0; i < 4; ++i)                                         \
            a[i] = *(const short8*)&(As)[(wr * 64 + i * 16 + l16) * 32 + xr]; \
        _Pragma("unroll")                                                   \
        for (int j = 0; j < 4; ++j)                                         \
            b[j] = *(const short8*)&(Bs)[(wc * 64 + j * 16 + l16) * 32 + xr]; \
        _Pragma("unroll")                                                   \
        for (int i = 0; i < 4; ++i)                                         \
            _Pragma("unroll")                                               \
            for (int j = 0; j < 4; ++j)                                     \
                acc[i][j] = mfma_bf16(a[i], b[j], acc[i][j]);               \
    }

    STAGE_G(A_s0, B_s0, 0);
    __syncthreads();

    for (int k0 = 0; k0 < K; k0 += 64) {
        if (k0 + 32 < K) { STAGE_G(A_s1, B_s1, k0 + 32); }
        COMPUTE_G(A_s0, B_s0);
        __syncthreads();
        if (k0 + 64 < K) { STAGE_G(A_s0, B_s0, k0 + 64); }
        COMPUTE_G(A_s1, B_s1);
        __syncthreads();
    }
#undef STAGE_G
#undef COMPUTE_G

    const float scale = (QSC && bn < 1024) ? QSCALE : 1.0f;
    #pragma unroll
    for (int i = 0; i < 4; ++i) {
        #pragma unroll
        for (int j = 0; j < 4; ++j) {
            #pragma unroll
            for (int r = 0; r < 4; ++r) {
                int row = bm + wr * 64 + i * 16 + quad * 4 + r;
                int col = bn + wc * 64 + j * 16 + l16;
                float v = acc[i][j][r] * scale;
                if (ADD_BIAS) v += bias[col];
                storeC(C, (size_t)row * N + col, v);
            }
        }
    }
}

// ---------------------------------------------------------------------------
// gemm64: BM=64, BN=128 variant of the same structure for the out-proj GEMM.
// Grid (8, 64) = 512 blocks -> 2 blocks/CU. 4 waves 2x2, per-wave 32x64.
// ---------------------------------------------------------------------------
template <bool ADD_BIAS, typename TC>
__global__ __launch_bounds__(256) void gemm64(
    const short* __restrict__ A, const short* __restrict__ Bt,
    const float* __restrict__ bias, TC* __restrict__ C,
    int M, int N, int K, int lda)
{
    __shared__ short A_s0[64 * 32];
    __shared__ short A_s1[64 * 32];
    __shared__ short B_s0[128 * 32];
    __shared__ short B_s1[128 * 32];
    const int tid  = threadIdx.x;
    const int lane = tid & 63;
    const int wave = tid >> 6;
    const int quad = lane >> 4;
    const int l16  = lane & 15;
    const int wr   = wave >> 1;     // M half (32 rows)
    const int wc   = wave & 1;      // N half (64 cols)
    const int bm   = blockIdx.y * 64;
    const int bn   = blockIdx.x * 128;

    f32x4 acc[2][4];
    #pragma unroll
    for (int i = 0; i < 2; ++i)
        #pragma unroll
        for (int j = 0; j < 4; ++j)
            acc[i][j] = f32x4{0.f, 0.f, 0.f, 0.f};

    const int srow = tid >> 2;
    const int schk = tid & 3;
    const int sg   = (schk ^ ((srow >> 1) & 3)) * 8;
    const short* ap0 = A  + (size_t)(bm + srow) * lda + sg;
    const short* bp0 = Bt + (size_t)(bn + srow) * K   + sg;
    const short* bp1 = Bt + (size_t)(bn + 64 + srow) * K + sg;
    const int lofs0 = wave * 512;
    const int lofs1 = 2048 + wave * 512;

    const int xr = (quad ^ ((l16 >> 1) & 3)) * 8;

#define STAGE_H(As, Bs, koff)                  \
    gload16(ap0 + (koff), (As) + lofs0);       \
    gload16(bp0 + (koff), (Bs) + lofs0);       \
    gload16(bp1 + (koff), (Bs) + lofs1);

#define COMPUTE_H(As, Bs)                                                   \
    {                                                                       \
        short8 a[2], b[4];                                                  \
        _Pragma("unroll")                                                   \
        for (int i = 0; i < 2; ++i)                                         \
            a[i] = *(const short8*)&(As)[(wr * 32 + i * 16 + l16) * 32 + xr]; \
        _Pragma("unroll")                                                   \
        for (int j = 0; j < 4; ++j)                                         \
            b[j] = *(const short8*)&(Bs)[(wc * 64 + j * 16 + l16) * 32 + xr]; \
        _Pragma("unroll")                                                   \
        for (int i = 0; i < 2; ++i)                                         \
            _Pragma("unroll")                                               \
            for (int j = 0; j < 4; ++j)                                     \
                acc[i][j] = mfma_bf16(a[i], b[j], acc[i][j]);               \
    }

    STAGE_H(A_s0, B_s0, 0);
    __syncthreads();

    for (int k0 = 0; k0 < K; k0 += 64) {
        if (k0 + 32 < K) { STAGE_H(A_s1, B_s1, k0 + 32); }
        COMPUTE_H(A_s0, B_s0);
        __syncthreads();
        if (k0 + 64 < K) { STAGE_H(A_s0, B_s0, k0 + 64); }
        COMPUTE_H(A_s1, B_s1);
        __syncthreads();
    }
#undef STAGE_H
#undef COMPUTE_H

    #pragma unroll
    for (int i = 0; i < 2; ++i) {
        #pragma unroll
        for (int j = 0; j < 4; ++j) {
            #pragma unroll
            for (int r = 0; r < 4; ++r) {
                int row = bm + wr * 32 + i * 16 + quad * 4 + r;
                int col = bn + wc * 64 + j * 16 + l16;
                float v = acc[i][j][r];
                if (ADD_BIAS) v += bias[col];
                storeC(C, (size_t)row * N + col, v);
            }
        }
    }
}

// ---------------------------------------------------------------------------
// Flash attention v8: 8-wave / 512-thread blocks, 16 q-rows per wave.
// Round-6 counters: MfmaUtil 35 / VALUBusy 38 / Occupancy 17% -> latency-
// bound at 2 waves/SIMD (grid 512 x 4 waves = 8 waves/CU). Same grid, 8
// waves/block -> 16 waves/CU = 4/SIMD: 2x the interleaving for the serial
// chain (K-frag ds_read -> S^T MFMA -> exp2 -> pack -> V ds_read -> PV).
// Per-lane math = old kernel with qg dimension removed (q = qb+wave*16+l16).
// K/V staging per block unchanged (16KB each per tile; 2 x short8/thread).
// __launch_bounds__(512,4) pins 4 waves/SIMD (VGPR <= 128).
// grid (2048/128, 32) = 512 blocks.
// ---------------------------------------------------------------------------
__global__ __launch_bounds__(512, 4) void attn128(
    short* __restrict__ qkv, const short* __restrict__ vt)
{
    __shared__ short Ks[128 * 72];   // [key][dim]
    __shared__ short Vs[16 * 520];   // [g][dim][k&7], g = key>>3 (tile-local)

    const int tid  = threadIdx.x;
    const int lane = tid & 63;
    const int wave = tid >> 6;       // 0..7
    const int quad = lane >> 4;
    const int l16  = lane & 15;
    const int bh   = blockIdx.y, b = bh >> 4, h = bh & 15;
    const int qb   = blockIdx.x * 128;
    const size_t rowbase = (size_t)b * 2048;

    // Q fragment: 16 q-rows per wave (q = qb + wave*16 + l16), pre-scaled
    short8 aq0, aq1;
    {
        const short* qp = qkv + (rowbase + qb + wave * 16 + l16) * 3072 + h * 64;
        aq0 = *(const short8*)(qp + quad * 8);
        aq1 = *(const short8*)(qp + 32 + quad * 8);
    }

    f32x4 o[4];
    #pragma unroll
    for (int c = 0; c < 4; ++c) o[c] = f32x4{0.f, 0.f, 0.f, 0.f};
    float rsum = 0.f;               // softmax denom partial for q = l16

    // staging maps (512 threads): K tile 128x64, V tile 64x128 (16KB each)
    const int kkey = tid >> 2, kdc = (tid & 3) * 16;
    const int vdim = tid >> 3, vg0 = (tid & 7) * 2;
    const short* kbase = qkv + (rowbase + kkey) * 3072 + 1024 + h * 64 + kdc;
    const short* vbase = vt + ((size_t)bh * 64 + vdim) * 2048 + vg0 * 8;

    // prefetch tile 0
    short8 kr0 = *(const short8*)(kbase);
    short8 kr1 = *(const short8*)(kbase + 8);
    short8 vr0 = *(const short8*)(vbase);
    short8 vr1 = *(const short8*)(vbase + 8);

    for (int kt = 0; kt < 2048; kt += 128) {
        __syncthreads();                      // prior-tile LDS readers done
        *(short8*)&Ks[kkey * 72 + kdc]     = kr0;
        *(short8*)&Ks[kkey * 72 + kdc + 8] = kr1;
        *(short8*)&Vs[(vg0 + 0) * 520 + vdim * 8] = vr0;
        *(short8*)&Vs[(vg0 + 1) * 520 + vdim * 8] = vr1;
        if (kt + 128 < 2048) {                // prefetch next tile
            const short* kp = kbase + (size_t)(kt + 128) * 3072;
            kr0 = *(const short8*)(kp);
            kr1 = *(const short8*)(kp + 8);
            const short* vp = vbase + kt + 128;
            vr0 = *(const short8*)(vp);
            vr1 = *(const short8*)(vp + 8);
        }
        __syncthreads();                      // tile visible

        // two chunks of 64 keys: S^T -> exp2 -> PV
        #pragma unroll
        for (int cc = 0; cc < 2; ++cc) {
            // S^T: lane holds S[q=l16][key=(cc*4+c4)*16+quad*4+r]
            f32x4 st[4];
            #pragma unroll
            for (int c4 = 0; c4 < 4; ++c4) {
                const int c = cc * 4 + c4;
                short8 ka0 = *(const short8*)&Ks[(c * 16 + l16) * 72 + quad * 8];
                short8 ka1 = *(const short8*)&Ks[(c * 16 + l16) * 72 + 32 + quad * 8];
                f32x4 z = f32x4{0.f, 0.f, 0.f, 0.f};
                z = mfma_bf16(ka0, aq0, z);
                st[c4] = mfma_bf16(ka1, aq1, z);
            }
            // p = exp2(s'): bare v_exp_f32 + v_cvt_pk_bf16_f32 packing
            uint2v pa[4];
            #pragma unroll
            for (int c4 = 0; c4 < 4; ++c4) {
                float p0 = fexp2(st[c4][0]);
                float p1 = fexp2(st[c4][1]);
                float p2 = fexp2(st[c4][2]);
                float p3 = fexp2(st[c4][3]);
                rsum += (p0 + p1) + (p2 + p3);
                uint2v pk;
                pk[0] = pkbf(p0, p1);
                pk[1] = pkbf(p2, p3);
                pa[c4] = pk;
            }
            // PV
            #pragma unroll
            for (int c2 = 0; c2 < 4; ++c2) {
                #pragma unroll
                for (int c4 = 0; c4 < 4; ++c4) {
                    const int c = cc * 4 + c4;
                    uint2v bv = *(const uint2v*)&Vs[(2 * c + (quad >> 1)) * 520
                                                    + (c2 * 16 + l16) * 8
                                                    + (quad & 1) * 4];
                    o[c2] = mfma16(pa[c4], bv, o[c2]);
                }
            }
        }
    }

    // full denom for q=l16: sum over the 4 quad-lanes
    rsum += __shfl_xor(rsum, 16, 64);
    rsum += __shfl_xor(rsum, 32, 64);

    // epilogue: o rows are q=quad*4+r; fetch that q's denom from lane q
    #pragma unroll
    for (int r = 0; r < 4; ++r) {
        float inv = 1.0f / __shfl(rsum, quad * 4 + r, 64);
        size_t row = rowbase + qb + wave * 16 + quad * 4 + r;
        #pragma unroll
        for (int c2 = 0; c2 < 4; ++c2)
            qkv[row * 3072 + h * 64 + c2 * 16 + l16] = f2b(o[c2][r] * inv);
    }
}

// ---------------------------------------------------------------------------
extern "C" void kernel_launch(void* const* d_in, const int* in_sizes, int n_in,
                              void* d_out, int out_size, void* d_ws, size_t ws_size,
                              hipStream_t stream)
{
    const float* x    = (const float*)d_in[0];   // (2,2048,1024) fp32
    const float* Wqkv = (const float*)d_in[2];   // (1024,3072) fp32
    const float* Wout = (const float*)d_in[3];   // (1024,1024) fp32
    const float* bout = (const float*)d_in[4];   // (1024,) fp32
    float* out = (float*)d_out;                  // (2,2048,1024) fp32

    // Buffer map:
    //   ws (32 MiB): qkv 24 MiB | wqkvt 6 MiB | woutt 2 MiB
    //   d_out (16 MiB): xbf lower 8 MiB (dead after gemm1)
    //                   vt  upper 8 MiB (dead after attn)
    //   gemm2 overwrites all of d_out last.
    short* qkv   = (short*)d_ws;                        // 4096 x 3072 bf16
    short* wqkvt = qkv + (size_t)4096 * 3072;           // 3072 x 1024 bf16
    short* woutt = wqkvt + (size_t)3072 * 1024;         // 1024 x 1024 bf16
    short* xbf   = (short*)d_out;                       // 4096 x 1024 bf16
    short* vtbuf = xbf + (size_t)4096 * 1024;           // 32 x 64 x 2048 bf16

    dim3 blk(256);
    prep<<<dim3(3072), blk, 0, stream>>>(x, xbf, Wqkv, wqkvt, Wout, woutt);
    gemm128<true, false, short><<<dim3(24, 32), blk, 0, stream>>>(
        xbf, wqkvt, nullptr, qkv, 4096, 3072, 1024, 1024);
    vtrans<<<dim3(32, 32), blk, 0, stream>>>(qkv, vtbuf);
    attn128<<<dim3(16, 32), dim3(512), 0, stream>>>(qkv, vtbuf);
    gemm64<true, float><<<dim3(8, 64), blk, 0, stream>>>(
        qkv, woutt, bout, out, 4096, 1024, 1024, 3072);
}

// Round 8
// 189.731 us; speedup vs baseline: 1.0322x; 1.0322x over previous
//
#include <hip/hip_runtime.h>

typedef __attribute__((ext_vector_type(8))) short short8;
typedef __attribute__((ext_vector_type(4))) short s16x4;
typedef __attribute__((ext_vector_type(8))) __bf16 bf16x8;
typedef __attribute__((ext_vector_type(4))) __bf16 bf16x4;
typedef __attribute__((ext_vector_type(2))) __bf16 bf16x2;
typedef __attribute__((ext_vector_type(4))) float f32x4;
typedef __attribute__((ext_vector_type(2))) float f32x2;
typedef __attribute__((ext_vector_type(4))) unsigned uint4v;
typedef __attribute__((ext_vector_type(2))) unsigned uint2v;

__device__ inline f32x4 mfma_bf16(short8 a, short8 b, f32x4 c) {
    return __builtin_amdgcn_mfma_f32_16x16x32_bf16(
        __builtin_bit_cast(bf16x8, a), __builtin_bit_cast(bf16x8, b), c, 0, 0, 0);
}
// K=16 bf16 MFMA: A-frag layout A[m=l16][k=quad*4+j] == C/D layout of a prior
// MFMA transposed -> P needs no layout transform.
__device__ inline f32x4 mfma16(uint2v a, uint2v b, f32x4 c) {
#if __has_builtin(__builtin_amdgcn_mfma_f32_16x16x16_bf16)
    return __builtin_amdgcn_mfma_f32_16x16x16_bf16(
        __builtin_bit_cast(bf16x4, a), __builtin_bit_cast(bf16x4, b), c, 0, 0, 0);
#else
    return __builtin_amdgcn_mfma_f32_16x16x16bf16_1k(
        __builtin_bit_cast(s16x4, a), __builtin_bit_cast(s16x4, b), c, 0, 0, 0);
#endif
}

// fast exp2: bare v_exp_f32
__device__ inline float fexp2(float x) {
#if __has_builtin(__builtin_amdgcn_exp2f)
    return __builtin_amdgcn_exp2f(x);
#else
    return exp2f(x);
#endif
}

// fp32 -> bf16 via HW convert (v_cvt_pk_bf16_f32 on gfx950), RNE
__device__ inline short f2b(float f) {
    __bf16 h = (__bf16)f;
    return __builtin_bit_cast(short, h);
}
__device__ inline unsigned pkbf(float a, float b) {
    f32x2 v; v[0] = a; v[1] = b;
    bf16x2 h = __builtin_convertvector(v, bf16x2);
    return __builtin_bit_cast(unsigned, h);
}

__device__ inline short8 ld8(const short* p) { return *(const short8*)p; }
__device__ inline short8 ld8(const float* p) {
    f32x4 a = *(const f32x4*)p;
    f32x4 b = *(const f32x4*)(p + 4);
    uint4v q;
    q[0] = pkbf(a[0], a[1]); q[1] = pkbf(a[2], a[3]);
    q[2] = pkbf(b[0], b[1]); q[3] = pkbf(b[2], b[3]);
    return __builtin_bit_cast(short8, q);
}
__device__ inline void storeC(short* C, size_t i, float v) { C[i] = f2b(v); }
__device__ inline void storeC(float* C, size_t i, float v) { C[i] = v; }

// async global->LDS DMA, 16B per lane. LDS dest must be wave-uniform base;
// HW writes lane l at base + l*16 (m104/m108: no per-lane LDS scatter).
__device__ inline void gload16(const short* g, short* l) {
    __builtin_amdgcn_global_load_lds(
        (const __attribute__((address_space(1))) unsigned*)g,
        (__attribute__((address_space(3))) unsigned*)l, 16, 0, 0);
}

// log2(e)/32 : folded into Q so softmax uses exp2 (bare v_exp_f32)
#define QSCALE 0.04508422052265167f

// ---------------------------------------------------------------------------
// Fused prep: one launch does
//   blocks [0,2048):    x fp32 -> xbf bf16 bulk convert
//   blocks [2048,2816): Wqkv [1024][3072] -> wqkvt [3072][1024] bf16 k-major
//   blocks [2816,3072): Wout [1024][1024] -> woutt [1024][1024] bf16 k-major
// ---------------------------------------------------------------------------
__global__ __launch_bounds__(256) void prep(
    const float* __restrict__ x, short* __restrict__ xb,
    const float* __restrict__ Wqkv, short* __restrict__ wqkvt,
    const float* __restrict__ Wout, short* __restrict__ woutt)
{
    const int bid = blockIdx.x;
    const int tid = threadIdx.x;
    if (bid < 2048) {
        size_t i = ((size_t)bid * 256 + tid) * 8;
        *(short8*)(xb + i) = ld8(x + i);
        return;
    }
    __shared__ short T[64 * 72];
    const float* W; short* Wt; int K, N, n0, k0;
    if (bid < 2816) {
        const int b2 = bid - 2048;
        W = Wqkv; Wt = wqkvt; K = 1024; N = 3072;
        n0 = (b2 % 48) * 64; k0 = (b2 / 48) * 64;
    } else {
        const int b3 = bid - 2816;
        W = Wout; Wt = woutt; K = 1024; N = 1024;
        n0 = (b3 & 15) * 64; k0 = (b3 >> 4) * 64;
    }
    {
        const int kl = tid >> 2, nc = (tid & 3) * 16;
        const float* src = W + (size_t)(k0 + kl) * N + n0 + nc;
        float v[16];
        *(f32x4*)&v[0]  = *(const f32x4*)(src + 0);
        *(f32x4*)&v[4]  = *(const f32x4*)(src + 4);
        *(f32x4*)&v[8]  = *(const f32x4*)(src + 8);
        *(f32x4*)&v[12] = *(const f32x4*)(src + 12);
        #pragma unroll
        for (int j = 0; j < 16; ++j) T[(nc + j) * 72 + kl] = f2b(v[j]);
    }
    __syncthreads();
    {
        const int nl = tid >> 2, kc = (tid & 3) * 16;
        short8 w0 = *(const short8*)&T[nl * 72 + kc];
        short8 w1 = *(const short8*)&T[nl * 72 + kc + 8];
        short* dst = Wt + (size_t)(n0 + nl) * K + k0 + kc;
        *(short8*)dst = w0;
        *(short8*)(dst + 8) = w1;
    }
}

// ---------------------------------------------------------------------------
// V transpose: qkv (B*N,3072) bf16 cols 2048+h*64 -> vt[(b*16+h)][dim][2048].
// ---------------------------------------------------------------------------
__global__ __launch_bounds__(256) void vtrans(
    const short* __restrict__ qkv, short* __restrict__ vt)
{
    __shared__ short T[64 * 72];
    const int tid = threadIdx.x;
    const int nt = blockIdx.x * 64, bh = blockIdx.y;
    const int b = bh >> 4, h = bh & 15;
    {
        const int tok = tid >> 2, dc = (tid & 3) * 16;
        const short* src = qkv + ((size_t)b * 2048 + nt + tok) * 3072 + 2048 + h * 64 + dc;
        short8 v0 = *(const short8*)src;
        short8 v1 = *(const short8*)(src + 8);
        #pragma unroll
        for (int j = 0; j < 8; ++j) {
            T[(dc + j) * 72 + tok]     = v0[j];
            T[(dc + 8 + j) * 72 + tok] = v1[j];
        }
    }
    __syncthreads();
    {
        const int dim = tid >> 2, kc = (tid & 3) * 16;
        short8 w0 = *(const short8*)&T[dim * 72 + kc];
        short8 w1 = *(const short8*)&T[dim * 72 + kc + 8];
        short* dst = vt + ((size_t)bh * 64 + dim) * 2048 + nt + kc;
        *(short8*)dst = w0;
        *(short8*)(dst + 8) = w1;
    }
}

// ---------------------------------------------------------------------------
// GEMM: global_load_lds DMA staging + double-buffered LDS 2-phase pipeline.
// C = A @ Bt^T (+bias). 128x128 tile, BK=32, 4 waves 2x2 (64x64 each).
// STAGE(next) issued BEFORE COMPUTE(cur); one barrier per K-step.
// Bank-swizzle: source chunk c ^ ((row>>1)&3), read slot quad ^ ((l16>>1)&3).
// __launch_bounds__(256,4): cap VGPR at 128 -> 4 waves/SIMD admissible, so
// ~3-4 blocks/CU co-resident (LDS 32KB -> 5). m97/m114: implicit wave-level
// overlap across co-resident blocks is what fills the barrier drain; a VGPR
// count >128 would halve that to 2 waves/SIMD (the m132-style cliff).
// QSC: scale cols<1024 by log2(e)/32 (Q pre-scale for exp2 softmax).
// ---------------------------------------------------------------------------
template <bool QSC, bool ADD_BIAS, typename TC>
__global__ __launch_bounds__(256, 4) void gemm128(
    const short* __restrict__ A, const short* __restrict__ Bt,
    const float* __restrict__ bias, TC* __restrict__ C,
    int M, int N, int K, int lda)
{
    __shared__ short A_s0[128 * 32];
    __shared__ short A_s1[128 * 32];
    __shared__ short B_s0[128 * 32];
    __shared__ short B_s1[128 * 32];
    const int tid  = threadIdx.x;
    const int lane = tid & 63;
    const int wave = tid >> 6;
    const int quad = lane >> 4;
    const int l16  = lane & 15;
    const int wr   = wave >> 1;
    const int wc   = wave & 1;
    const int bm   = blockIdx.y * 128;
    const int bn   = blockIdx.x * 128;

    f32x4 acc[4][4];
    #pragma unroll
    for (int i = 0; i < 4; ++i)
        #pragma unroll
        for (int j = 0; j < 4; ++j)
            acc[i][j] = f32x4{0.f, 0.f, 0.f, 0.f};

    const int srow = tid >> 2;
    const int schk = tid & 3;
    const int sg   = (schk ^ ((srow >> 1) & 3)) * 8;
    const short* ap0 = A  + (size_t)(bm + srow) * lda + sg;
    const short* ap1 = A  + (size_t)(bm + 64 + srow) * lda + sg;
    const short* bp0 = Bt + (size_t)(bn + srow) * K   + sg;
    const short* bp1 = Bt + (size_t)(bn + 64 + srow) * K   + sg;
    const int lofs0 = wave * 512;
    const int lofs1 = 2048 + wave * 512;

    const int xr = (quad ^ ((l16 >> 1) & 3)) * 8;

#define STAGE_G(As, Bs, koff)                  \
    gload16(ap0 + (koff), (As) + lofs0);       \
    gload16(ap1 + (koff), (As) + lofs1);       \
    gload16(bp0 + (koff), (Bs) + lofs0);       \
    gload16(bp1 + (koff), (Bs) + lofs1);

#define COMPUTE_G(As, Bs)                                                   \
    {                                                                       \
        short8 a[4], b[4];                                                  \
        _Pragma("unroll")                                                   \
        for (int i = 0; i < 4; ++i)                                         \
            a[i] = *(const short8*)&(As)[(wr * 64 + i * 16 + l16) * 32 + xr]; \
        _Pragma("unroll")                                                   \
        for (int j = 0; j < 4; ++j)                                         \
            b[j] = *(const short8*)&(Bs)[(wc * 64 + j * 16 + l16) * 32 + xr]; \
        _Pragma("unroll")                                                   \
        for (int i = 0; i < 4; ++i)                                         \
            _Pragma("unroll")                                               \
            for (int j = 0; j < 4; ++j)                                     \
                acc[i][j] = mfma_bf16(a[i], b[j], acc[i][j]);               \
    }

    STAGE_G(A_s0, B_s0, 0);
    __syncthreads();

    for (int k0 = 0; k0 < K; k0 += 64) {
        if (k0 + 32 < K) { STAGE_G(A_s1, B_s1, k0 + 32); }
        COMPUTE_G(A_s0, B_s0);
        __syncthreads();
        if (k0 + 64 < K) { STAGE_G(A_s0, B_s0, k0 + 64); }
        COMPUTE_G(A_s1, B_s1);
        __syncthreads();
    }
#undef STAGE_G
#undef COMPUTE_G

    const float scale = (QSC && bn < 1024) ? QSCALE : 1.0f;
    #pragma unroll
    for (int i = 0; i < 4; ++i) {
        #pragma unroll
        for (int j = 0; j < 4; ++j) {
            #pragma unroll
            for (int r = 0; r < 4; ++r) {
                int row = bm + wr * 64 + i * 16 + quad * 4 + r;
                int col = bn + wc * 64 + j * 16 + l16;
                float v = acc[i][j][r] * scale;
                if (ADD_BIAS) v += bias[col];
                storeC(C, (size_t)row * N + col, v);
            }
        }
    }
}

// ---------------------------------------------------------------------------
// gemm64: BM=64, BN=128 variant of the same structure for the out-proj GEMM.
// Grid (8, 64) = 512 blocks -> 2 blocks/CU. 4 waves 2x2, per-wave 32x64.
// ---------------------------------------------------------------------------
template <bool ADD_BIAS, typename TC>
__global__ __launch_bounds__(256, 4) void gemm64(
    const short* __restrict__ A, const short* __restrict__ Bt,
    const float* __restrict__ bias, TC* __restrict__ C,
    int M, int N, int K, int lda)
{
    __shared__ short A_s0[64 * 32];
    __shared__ short A_s1[64 * 32];
    __shared__ short B_s0[128 * 32];
    __shared__ short B_s1[128 * 32];
    const int tid  = threadIdx.x;
    const int lane = tid & 63;
    const int wave = tid >> 6;
    const int quad = lane >> 4;
    const int l16  = lane & 15;
    const int wr   = wave >> 1;     // M half (32 rows)
    const int wc   = wave & 1;      // N half (64 cols)
    const int bm   = blockIdx.y * 64;
    const int bn   = blockIdx.x * 128;

    f32x4 acc[2][4];
    #pragma unroll
    for (int i = 0; i < 2; ++i)
        #pragma unroll
        for (int j = 0; j < 4; ++j)
            acc[i][j] = f32x4{0.f, 0.f, 0.f, 0.f};

    const int srow = tid >> 2;
    const int schk = tid & 3;
    const int sg   = (schk ^ ((srow >> 1) & 3)) * 8;
    const short* ap0 = A  + (size_t)(bm + srow) * lda + sg;
    const short* bp0 = Bt + (size_t)(bn + srow) * K   + sg;
    const short* bp1 = Bt + (size_t)(bn + 64 + srow) * K + sg;
    const int lofs0 = wave * 512;
    const int lofs1 = 2048 + wave * 512;

    const int xr = (quad ^ ((l16 >> 1) & 3)) * 8;

#define STAGE_H(As, Bs, koff)                  \
    gload16(ap0 + (koff), (As) + lofs0);       \
    gload16(bp0 + (koff), (Bs) + lofs0);       \
    gload16(bp1 + (koff), (Bs) + lofs1);

#define COMPUTE_H(As, Bs)                                                   \
    {                                                                       \
        short8 a[2], b[4];                                                  \
        _Pragma("unroll")                                                   \
        for (int i = 0; i < 2; ++i)                                         \
            a[i] = *(const short8*)&(As)[(wr * 32 + i * 16 + l16) * 32 + xr]; \
        _Pragma("unroll")                                                   \
        for (int j = 0; j < 4; ++j)                                         \
            b[j] = *(const short8*)&(Bs)[(wc * 64 + j * 16 + l16) * 32 + xr]; \
        _Pragma("unroll")                                                   \
        for (int i = 0; i < 2; ++i)                                         \
            _Pragma("unroll")                                               \
            for (int j = 0; j < 4; ++j)                                     \
                acc[i][j] = mfma_bf16(a[i], b[j], acc[i][j]);               \
    }

    STAGE_H(A_s0, B_s0, 0);
    __syncthreads();

    for (int k0 = 0; k0 < K; k0 += 64) {
        if (k0 + 32 < K) { STAGE_H(A_s1, B_s1, k0 + 32); }
        COMPUTE_H(A_s0, B_s0);
        __syncthreads();
        if (k0 + 64 < K) { STAGE_H(A_s0, B_s0, k0 + 64); }
        COMPUTE_H(A_s1, B_s1);
        __syncthreads();
    }
#undef STAGE_H
#undef COMPUTE_H

    #pragma unroll
    for (int i = 0; i < 2; ++i) {
        #pragma unroll
        for (int j = 0; j < 4; ++j) {
            #pragma unroll
            for (int r = 0; r < 4; ++r) {
                int row = bm + wr * 32 + i * 16 + quad * 4 + r;
                int col = bn + wc * 64 + j * 16 + l16;
                float v = acc[i][j][r];
                if (ADD_BIAS) v += bias[col];
                storeC(C, (size_t)row * N + col, v);
            }
        }
    }
}

// ---------------------------------------------------------------------------
// Flash attention v7 (round-6 version — measured 57.4-57.6 µs across 4 runs).
// Round-7 lesson: halving q-rows/wave (8-wave/16q) doubled per-wave LDS
// traffic (every wave reads the whole K/V tile) -> conflicts 7.3M->13.6M,
// 64.6 µs. This structure is LDS-read-bound via the q-amortization factor;
// occupancy moves that scale LDS traffic are net-negative.
// 32 q-rows per wave; S^T MFMA -> exp2 -> direct K=16 PV; ctx in-place.
// grid (2048/128, 32) = 512 blocks.
// ---------------------------------------------------------------------------
__global__ __launch_bounds__(256) void attn128(
    short* __restrict__ qkv, const short* __restrict__ vt)
{
    __shared__ short Ks[128 * 72];   // [key][dim]
    __shared__ short Vs[16 * 520];   // [g][dim][k&7], g = key>>3 (tile-local)

    const int tid  = threadIdx.x;
    const int lane = tid & 63;
    const int wave = tid >> 6;
    const int quad = lane >> 4;
    const int l16  = lane & 15;
    const int bh   = blockIdx.y, b = bh >> 4, h = bh & 15;
    const int qb   = blockIdx.x * 128;
    const size_t rowbase = (size_t)b * 2048;

    // Q fragments for 2 q-groups (B-op for S^T), pre-scaled by log2e/32
    short8 aq[2][2];
    #pragma unroll
    for (int qg = 0; qg < 2; ++qg) {
        const short* qp = qkv + (rowbase + qb + wave * 32 + qg * 16 + l16) * 3072 + h * 64;
        aq[qg][0] = *(const short8*)(qp + quad * 8);
        aq[qg][1] = *(const short8*)(qp + 32 + quad * 8);
    }

    f32x4 o[2][4];
    #pragma unroll
    for (int qg = 0; qg < 2; ++qg)
        #pragma unroll
        for (int c = 0; c < 4; ++c) o[qg][c] = f32x4{0.f, 0.f, 0.f, 0.f};
    float rsum[2] = {0.f, 0.f};   // softmax denom partials for q = l16

    const int kkey = tid >> 1, kdc = (tid & 1) * 32;
    const int vdim = tid >> 2, vg0 = (tid & 3) * 4;
    const short* kbase = qkv + (rowbase + kkey) * 3072 + 1024 + h * 64 + kdc;
    const short* vbase = vt + ((size_t)bh * 64 + vdim) * 2048 + vg0 * 8;

    // prefetch tile 0
    short8 kr0 = *(const short8*)(kbase);
    short8 kr1 = *(const short8*)(kbase + 8);
    short8 kr2 = *(const short8*)(kbase + 16);
    short8 kr3 = *(const short8*)(kbase + 24);
    short8 vr0 = *(const short8*)(vbase);
    short8 vr1 = *(const short8*)(vbase + 8);
    short8 vr2 = *(const short8*)(vbase + 16);
    short8 vr3 = *(const short8*)(vbase + 24);

    for (int kt = 0; kt < 2048; kt += 128) {
        __syncthreads();                      // prior-tile LDS readers done
        *(short8*)&Ks[kkey * 72 + kdc]      = kr0;
        *(short8*)&Ks[kkey * 72 + kdc + 8]  = kr1;
        *(short8*)&Ks[kkey * 72 + kdc + 16] = kr2;
        *(short8*)&Ks[kkey * 72 + kdc + 24] = kr3;
        *(short8*)&Vs[(vg0 + 0) * 520 + vdim * 8] = vr0;
        *(short8*)&Vs[(vg0 + 1) * 520 + vdim * 8] = vr1;
        *(short8*)&Vs[(vg0 + 2) * 520 + vdim * 8] = vr2;
        *(short8*)&Vs[(vg0 + 3) * 520 + vdim * 8] = vr3;
        if (kt + 128 < 2048) {                // prefetch next tile
            const short* kp = kbase + (size_t)(kt + 128) * 3072;
            kr0 = *(const short8*)(kp);
            kr1 = *(const short8*)(kp + 8);
            kr2 = *(const short8*)(kp + 16);
            kr3 = *(const short8*)(kp + 24);
            const short* vp = vbase + kt + 128;
            vr0 = *(const short8*)(vp);
            vr1 = *(const short8*)(vp + 8);
            vr2 = *(const short8*)(vp + 16);
            vr3 = *(const short8*)(vp + 24);
        }
        __syncthreads();                      // tile visible

        // two chunks of 64 keys: S^T -> exp2 -> PV
        #pragma unroll
        for (int cc = 0; cc < 2; ++cc) {
            // S^T: lane holds S[q=l16][key=(cc*4+c4)*16+quad*4+r], per q-group
            f32x4 st[2][4];
            #pragma unroll
            for (int c4 = 0; c4 < 4; ++c4) {
                const int c = cc * 4 + c4;
                short8 ka0 = *(const short8*)&Ks[(c * 16 + l16) * 72 + quad * 8];
                short8 ka1 = *(const short8*)&Ks[(c * 16 + l16) * 72 + 32 + quad * 8];
                #pragma unroll
                for (int qg = 0; qg < 2; ++qg) {
                    f32x4 z = f32x4{0.f, 0.f, 0.f, 0.f};
                    z = mfma_bf16(ka0, aq[qg][0], z);
                    st[qg][c4] = mfma_bf16(ka1, aq[qg][1], z);
                }
            }
            // p = exp2(s'): bare v_exp_f32 + v_cvt_pk_bf16_f32 packing
            uint2v pa[2][4];
            #pragma unroll
            for (int qg = 0; qg < 2; ++qg) {
                #pragma unroll
                for (int c4 = 0; c4 < 4; ++c4) {
                    float p0 = fexp2(st[qg][c4][0]);
                    float p1 = fexp2(st[qg][c4][1]);
                    float p2 = fexp2(st[qg][c4][2]);
                    float p3 = fexp2(st[qg][c4][3]);
                    rsum[qg] += (p0 + p1) + (p2 + p3);
                    uint2v pk;
                    pk[0] = pkbf(p0, p1);
                    pk[1] = pkbf(p2, p3);
                    pa[qg][c4] = pk;
                }
            }
            // PV: bv read once, used by both q-groups
            #pragma unroll
            for (int c2 = 0; c2 < 4; ++c2) {
                #pragma unroll
                for (int c4 = 0; c4 < 4; ++c4) {
                    const int c = cc * 4 + c4;
                    uint2v bv = *(const uint2v*)&Vs[(2 * c + (quad >> 1)) * 520
                                                    + (c2 * 16 + l16) * 8
                                                    + (quad & 1) * 4];
                    #pragma unroll
                    for (int qg = 0; qg < 2; ++qg)
                        o[qg][c2] = mfma16(pa[qg][c4], bv, o[qg][c2]);
                }
            }
        }
    }

    // full denom for q=l16: sum over the 4 quad-lanes
    #pragma unroll
    for (int qg = 0; qg < 2; ++qg) {
        rsum[qg] += __shfl_xor(rsum[qg], 16, 64);
        rsum[qg] += __shfl_xor(rsum[qg], 32, 64);
    }

    // epilogue: o rows are q=quad*4+r; fetch that q's denom from lane q
    #pragma unroll
    for (int qg = 0; qg < 2; ++qg) {
        #pragma unroll
        for (int r = 0; r < 4; ++r) {
            float inv = 1.0f / __shfl(rsum[qg], quad * 4 + r, 64);
            size_t row = rowbase + qb + wave * 32 + qg * 16 + quad * 4 + r;
            #pragma unroll
            for (int c2 = 0; c2 < 4; ++c2)
                qkv[row * 3072 + h * 64 + c2 * 16 + l16] = f2b(o[qg][c2][r] * inv);
        }
    }
}

// ---------------------------------------------------------------------------
extern "C" void kernel_launch(void* const* d_in, const int* in_sizes, int n_in,
                              void* d_out, int out_size, void* d_ws, size_t ws_size,
                              hipStream_t stream)
{
    const float* x    = (const float*)d_in[0];   // (2,2048,1024) fp32
    const float* Wqkv = (const float*)d_in[2];   // (1024,3072) fp32
    const float* Wout = (const float*)d_in[3];   // (1024,1024) fp32
    const float* bout = (const float*)d_in[4];   // (1024,) fp32
    float* out = (float*)d_out;                  // (2,2048,1024) fp32

    // Buffer map:
    //   ws (32 MiB): qkv 24 MiB | wqkvt 6 MiB | woutt 2 MiB
    //   d_out (16 MiB): xbf lower 8 MiB (dead after gemm1)
    //                   vt  upper 8 MiB (dead after attn)
    //   gemm2 overwrites all of d_out last.
    short* qkv   = (short*)d_ws;                        // 4096 x 3072 bf16
    short* wqkvt = qkv + (size_t)4096 * 3072;           // 3072 x 1024 bf16
    short* woutt = wqkvt + (size_t)3072 * 1024;         // 1024 x 1024 bf16
    short* xbf   = (short*)d_out;                       // 4096 x 1024 bf16
    short* vtbuf = xbf + (size_t)4096 * 1024;           // 32 x 64 x 2048 bf16

    dim3 blk(256);
    prep<<<dim3(3072), blk, 0, stream>>>(x, xbf, Wqkv, wqkvt, Wout, woutt);
    gemm128<true, false, short><<<dim3(24, 32), blk, 0, stream>>>(
        xbf, wqkvt, nullptr, qkv, 4096, 3072, 1024, 1024);
    vtrans<<<dim3(32, 32), blk, 0, stream>>>(qkv, vtbuf);
    attn128<<<dim3(16, 32), blk, 0, stream>>>(qkv, vtbuf);
    gemm64<true, float><<<dim3(8, 64), blk, 0, stream>>>(
        qkv, woutt, bout, out, 4096, 1024, 1024, 3072);
}